// Round 4
// baseline (293.722 us; speedup 1.0000x reference)
//
#include <hip/hip_runtime.h>
#include <hip/hip_bf16.h>

#define FIN 4096
#define FOUT 4096
#define HEADS 4
#define ROWS_PER_HEAD (FOUT / HEADS)  // 1024
#define M_DIM 4096                    // 2*2048 flattened batch*seq

typedef __attribute__((ext_vector_type(8))) short bf16x8;   // 8 bf16 = 4 VGPRs
typedef __attribute__((ext_vector_type(4))) float floatx4;  // MFMA accum

#define CAST_BLOCKS ((M_DIM * FIN) / (256 * 8))      // 8192
#define TRANS_BLOCKS ((FOUT * FIN / 8) / 256)        // 8192

// ---------------------------------------------------------------------------
// Kernel 1 (merged prep, unchanged from R5-verified).
// ---------------------------------------------------------------------------
__global__ __launch_bounds__(256) void prep(
    const float* __restrict__ x,    // activations [M_DIM][FIN]
    __hip_bfloat16* __restrict__ y, // bf16 activations out
    const float* __restrict__ W,
    const float* __restrict__ cw,   // [HEADS][3][3]
    const float* __restrict__ cb,   // [HEADS]
    const float* __restrict__ sk,   // [HEADS]
    __hip_bfloat16* __restrict__ Wt) {
  if (blockIdx.x < CAST_BLOCKS) {
    int idx = blockIdx.x * 256 + threadIdx.x;  // one per 8 elements
    const float4* xv = (const float4*)x;
    float4 a = xv[idx * 2];
    float4 b = xv[idx * 2 + 1];
    __hip_bfloat16 t[8];
    t[0] = __float2bfloat16(a.x); t[1] = __float2bfloat16(a.y);
    t[2] = __float2bfloat16(a.z); t[3] = __float2bfloat16(a.w);
    t[4] = __float2bfloat16(b.x); t[5] = __float2bfloat16(b.y);
    t[6] = __float2bfloat16(b.z); t[7] = __float2bfloat16(b.w);
    *(bf16x8*)(&y[(size_t)idx * 8]) = *(bf16x8*)t;
    return;
  }

  int gid = (blockIdx.x - CAST_BLOCKS) * 256 + threadIdx.x;
  int o = gid >> 9;                          // output row (FIN/8 = 512)
  int fs = (gid & 511) << 3;                 // fin start, multiple of 8
  int h = o >> 10;                           // head
  int r = o & (ROWS_PER_HEAD - 1);

  float kk[3][3];
#pragma unroll
  for (int i = 0; i < 3; i++)
#pragma unroll
    for (int j = 0; j < 3; j++) kk[i][j] = cw[h * 9 + i * 3 + j];
  float sig = 1.0f / (1.0f + __expf(-sk[h]));

  float acc[8];
#pragma unroll
  for (int j = 0; j < 8; j++) acc[j] = cb[h];

#pragma unroll
  for (int dr = -1; dr <= 1; dr++) {
    int rr = r + dr;
    if (rr < 0 || rr >= ROWS_PER_HEAD) continue;
    const float* rp = W + ((size_t)(h * ROWS_PER_HEAD + rr)) * FIN + fs;
    float a[10];
    float4 v0 = *(const float4*)rp;
    float4 v1 = *(const float4*)(rp + 4);
    a[1] = v0.x; a[2] = v0.y; a[3] = v0.z; a[4] = v0.w;
    a[5] = v1.x; a[6] = v1.y; a[7] = v1.z; a[8] = v1.w;
    a[0] = (fs > 0) ? rp[-1] : 0.0f;
    a[9] = (fs + 8 < FIN) ? rp[8] : 0.0f;
#pragma unroll
    for (int j = 0; j < 8; j++)
      acc[j] += kk[dr + 1][0] * a[j] + kk[dr + 1][1] * a[j + 1] +
                kk[dr + 1][2] * a[j + 2];
    if (dr == 0) {
#pragma unroll
      for (int j = 0; j < 8; j++) acc[j] += sig * a[j + 1];
    }
  }
  __hip_bfloat16 t[8];
#pragma unroll
  for (int j = 0; j < 8; j++) t[j] = __float2bfloat16(acc[j]);
  *(bf16x8*)(&Wt[(size_t)o * FIN + fs]) = *(bf16x8*)t;
}

// ---------------------------------------------------------------------------
// Kernel 2: C[m][n] = sum_k A[m][k] * B[n][k]  (NT GEMM, bf16 in, FP32 out)
// R11: faithful m201 8-phase port. One ITERATION = 2 K-tiles (even tile in
// buf0, odd in buf1 -- buffer roles FIXED, no runtime indexing). Per phase:
// {ds_read quadrant frags; stage exactly 1 half-tile; [lgkmcnt(8) on the
// 12-read phases]; s_barrier; lgkmcnt(0); setprio(1); 16 MFMA; setprio(0);
// s_barrier}. vmcnt(6) ONLY at phases 4 and 8, before the closing barrier:
// each covers a stage issued a full 4 phases earlier (3 half-tiles / 6 loads
// stay in flight -- never drains). NO sched_barrier (m141 failure mode).
//
// Stage schedule (iteration at even tile T):
//   ph1 -> B-h0 of T+1 (buf1)    [completes buf1 for ph5..8; vmcnt(6)@ph4]
//   ph2 -> A-h0 of T+2 (buf0, died ph1)   ph3 -> B-h1 of T+2 (died ph2)
//   ph4 -> A-h1 of T+2 (died ph3)         ph5 -> B-h0 of T+2 (died ph1)
//   ph6 -> A-h0 of T+3 (buf1, died ph5)   ph7 -> B-h1 of T+3 (died ph6)
//   ph8 -> A-h1 of T+3 (died ph7)         [next-iter ph1 -> B-h0 of T+3]
// Every stage target's last reader was sealed by lgkm(0)+barrier >=1 phase
// earlier; every read target's stage is sealed by vmcnt+barrier earlier.
// Steady state: exactly 6 loads outstanding entering each iteration.
// Quadrant order per tile: (0,0),(0,1),(1,1),(1,0); B-h0 frags held in regs
// ph1->ph4, A-h1 frags ph3->ph4 (ph4/ph8 issue ZERO ds_reads).
// ---------------------------------------------------------------------------
__device__ static inline void gload_lds16(const void* g, void* l) {
  __builtin_amdgcn_global_load_lds(
      (const __attribute__((address_space(1))) void*)g,
      (__attribute__((address_space(3))) void*)l, 16, 0, 0);
}

#define BK 64
#define NT (FIN / BK)  // 64 K-tiles

__global__ __launch_bounds__(512, 2) void gemm_nt(
    const __hip_bfloat16* __restrict__ A,  // [M][K]
    const __hip_bfloat16* __restrict__ B,  // [N][K]  (= W_i, row-major)
    float* __restrict__ C,                 // [M][N] fp32
    int M, int N, int K) {
  // 8 distinct LDS objects (precise DMA alias info): 16 KB each, 128 KB.
  __shared__ __hip_bfloat16 As0h0[128 * BK];
  __shared__ __hip_bfloat16 As0h1[128 * BK];
  __shared__ __hip_bfloat16 As1h0[128 * BK];
  __shared__ __hip_bfloat16 As1h1[128 * BK];
  __shared__ __hip_bfloat16 Bs0h0[128 * BK];
  __shared__ __hip_bfloat16 Bs0h1[128 * BK];
  __shared__ __hip_bfloat16 Bs1h0[128 * BK];
  __shared__ __hip_bfloat16 Bs1h1[128 * BK];

  const int tid = threadIdx.x;
  const int lane = tid & 63;
  const int wave = tid >> 6;   // 0..7
  const int wr = wave >> 2;    // 0..1  (WARPS_M = 2)
  const int wn = wave & 3;     // 0..3  (WARPS_N = 4)
  const int fr = lane & 15;    // fragment row
  const int quad = lane >> 4;  // k-chunk selector
  const int sel = fr & 7;      // swizzle selector

  // XCD-chunked bijective swizzle (256 wgs % 8 == 0): 32 consecutive tiles
  // per XCD -> 2 A-panels (4 MB) L2-resident per XCD (mechanism confirmed
  // in R9: HBM BW 1490->990 GB/s at same FETCH).
  const int orig = blockIdx.y * gridDim.x + blockIdx.x;
  const int swz = (orig & 7) * 32 + (orig >> 3);
  const int tile_m = (swz >> 4) * 256;
  const int tile_n = (swz & 15) * 256;

  const __hip_bfloat16* At = A + (size_t)tile_m * K;  // SGPR base
  const __hip_bfloat16* Bt = B + (size_t)tile_n * K;

  // Staging invariants: chunk position p = c*512+tid; row=p>>3, slot=p&7
  // holds global chunk g = slot^(row&7)  (proven conflict-free swizzle).
  int soff[2], doff[2];
#pragma unroll
  for (int c = 0; c < 2; c++) {
    int p = c * 512 + tid;
    int row = p >> 3;
    int g = (p & 7) ^ (row & 7);
    soff[c] = row * K + g * 8;  // elems
    doff[c] = p * 8;            // elems into half-buffer
  }
  // Fragment read invariants (all local rows == fr mod 8 -> sel works).
  int aro[4], bro[2], co[2];
#pragma unroll
  for (int u = 0; u < 4; u++) aro[u] = (wr * 16 + u * 32 + fr) * 64;
#pragma unroll
  for (int j = 0; j < 2; j++) bro[j] = (wn * 16 + j * 64 + fr) * 64;
#pragma unroll
  for (int kk = 0; kk < 2; kk++) co[kk] = ((kk * 4 + quad) ^ sel) * 8;

  floatx4 acc[8][4];
#pragma unroll
  for (int i = 0; i < 8; i++)
#pragma unroll
    for (int j = 0; j < 4; j++) acc[i][j] = (floatx4){0.f, 0.f, 0.f, 0.f};

  bf16x8 af[4][2];     // A frags of current m-half: [u][kk]
  bf16x8 bf[2][2][2];  // B frags: [nh][j][kk]; nh=0 held ph1->ph4

#define STAGE(GBASE, DST, TILE, HALF)                                    \
  do {                                                                   \
    const __hip_bfloat16* _s =                                           \
        GBASE + (size_t)(HALF) * 128 * K + (size_t)(TILE) * BK;          \
    _Pragma("unroll") for (int _c = 0; _c < 2; _c++) {                   \
      gload_lds16(_s + soff[_c], DST + doff[_c]);                        \
    }                                                                    \
  } while (0)

#define LOADA_H(SRC)                                                     \
  do {                                                                   \
    _Pragma("unroll") for (int _u = 0; _u < 4; _u++) {                   \
      _Pragma("unroll") for (int _kk = 0; _kk < 2; _kk++) {              \
        af[_u][_kk] = *(const bf16x8*)&SRC[aro[_u] + co[_kk]];           \
      }                                                                  \
    }                                                                    \
  } while (0)

#define LOADB_H(NH, SRC)                                                 \
  do {                                                                   \
    _Pragma("unroll") for (int _j = 0; _j < 2; _j++) {                   \
      _Pragma("unroll") for (int _kk = 0; _kk < 2; _kk++) {              \
        bf[NH][_j][_kk] = *(const bf16x8*)&SRC[bro[_j] + co[_kk]];       \
      }                                                                  \
    }                                                                    \
  } while (0)

#define MMA16(MH, NH)                                                    \
  do {                                                                   \
    __builtin_amdgcn_s_setprio(1);                                       \
    _Pragma("unroll") for (int _kk = 0; _kk < 2; _kk++) {                \
      _Pragma("unroll") for (int _u = 0; _u < 4; _u++) {                 \
        _Pragma("unroll") for (int _j = 0; _j < 2; _j++) {               \
          acc[(MH) * 4 + _u][(NH) * 2 + _j] =                            \
              __builtin_amdgcn_mfma_f32_16x16x32_bf16(                   \
                  af[_u][_kk], bf[NH][_j][_kk],                          \
                  acc[(MH) * 4 + _u][(NH) * 2 + _j], 0, 0, 0);           \
        }                                                                \
      }                                                                  \
    }                                                                    \
    __builtin_amdgcn_s_setprio(0);                                       \
  } while (0)

#define BAR() __builtin_amdgcn_s_barrier()
#define VMC(N) asm volatile("s_waitcnt vmcnt(" #N ")" ::: "memory")
#define LGKM(N) asm volatile("s_waitcnt lgkmcnt(" #N ")" ::: "memory")

  // ---- Prologue: tile0 fully into buf0 (first 8 loads), then tile1's
  // A-h0/B-h1/A-h1 into buf1 (6 loads). vmcnt(6) completes exactly tile0.
  STAGE(At, As0h0, 0, 0);
  STAGE(Bt, Bs0h0, 0, 0);
  STAGE(Bt, Bs0h1, 0, 1);
  STAGE(At, As0h1, 0, 1);
  STAGE(At, As1h0, 1, 0);
  STAGE(Bt, Bs1h1, 1, 1);
  STAGE(At, As1h1, 1, 1);
  VMC(6);
  BAR();

  // ---- Main loop: iterations 0..30 (tiles 0..61). 6 loads outstanding at
  // each iteration entry (prev ph6/7/8 stages).
#pragma unroll 1
  for (int it = 0; it < (NT / 2) - 1; ++it) {
    const int T = it * 2;
    // ph1: Q00 of tile T (12 reads)
    LOADA_H(As0h0);
    LOADB_H(0, Bs0h0);
    STAGE(Bt, Bs1h0, T + 1, 0);
    LGKM(8);
    BAR(); LGKM(0); MMA16(0, 0); BAR();
    // ph2: Q01 (4 reads)
    LOADB_H(1, Bs0h1);
    STAGE(At, As0h0, T + 2, 0);
    BAR(); LGKM(0); MMA16(0, 1); BAR();
    // ph3: Q11 (8 reads)
    LOADA_H(As0h1);
    STAGE(Bt, Bs0h1, T + 2, 1);
    BAR(); LGKM(0); MMA16(1, 1); BAR();
    // ph4: Q10 (0 reads; af=m1, bf[0] held since ph1)
    STAGE(At, As0h1, T + 2, 1);
    BAR(); MMA16(1, 0); VMC(6); BAR();
    // ph5: Q00 of tile T+1 (12 reads)
    LOADA_H(As1h0);
    LOADB_H(0, Bs1h0);
    STAGE(Bt, Bs0h0, T + 2, 0);
    LGKM(8);
    BAR(); LGKM(0); MMA16(0, 0); BAR();
    // ph6: Q01 (4 reads)
    LOADB_H(1, Bs1h1);
    STAGE(At, As1h0, T + 3, 0);
    BAR(); LGKM(0); MMA16(0, 1); BAR();
    // ph7: Q11 (8 reads)
    LOADA_H(As1h1);
    STAGE(Bt, Bs1h1, T + 3, 1);
    BAR(); LGKM(0); MMA16(1, 1); BAR();
    // ph8: Q10 (0 reads)
    STAGE(At, As1h1, T + 3, 1);
    BAR(); MMA16(1, 0); VMC(6); BAR();
  }

  // ---- Tail iteration (tiles 62, 63): only ph1's stage (B-h0 of 63);
  // vmcnt(0) at ph4 seals tile 63 (8 loads outstanding there).
  {
    LOADA_H(As0h0);
    LOADB_H(0, Bs0h0);
    STAGE(Bt, Bs1h0, NT - 1, 0);
    LGKM(8);
    BAR(); LGKM(0); MMA16(0, 0); BAR();
    LOADB_H(1, Bs0h1);
    BAR(); LGKM(0); MMA16(0, 1); BAR();
    LOADA_H(As0h1);
    BAR(); LGKM(0); MMA16(1, 1); BAR();
    BAR(); MMA16(1, 0); VMC(0); BAR();
    LOADA_H(As1h0);
    LOADB_H(0, Bs1h0);
    BAR(); LGKM(0); MMA16(0, 0); BAR();
    LOADB_H(1, Bs1h1);
    BAR(); LGKM(0); MMA16(0, 1); BAR();
    LOADA_H(As1h1);
    BAR(); LGKM(0); MMA16(1, 1); BAR();
    BAR(); MMA16(1, 0);
  }

#undef STAGE
#undef LOADA_H
#undef LOADB_H
#undef MMA16
#undef BAR
#undef VMC
#undef LGKM

  // ---- Epilogue: C/D layout col = lane&15, row = quad*4 + reg.
#pragma unroll
  for (int i = 0; i < 8; i++) {
    int mb = tile_m + wr * 16 + i * 32 + quad * 4;
#pragma unroll
    for (int j = 0; j < 4; j++) {
      int n = tile_n + wn * 16 + j * 64 + fr;
#pragma unroll
      for (int r = 0; r < 4; r++) {
        C[(size_t)(mb + r) * N + n] = acc[i][j][r];
      }
    }
  }
}

// ---------------------------------------------------------------------------
extern "C" void kernel_launch(void* const* d_in, const int* in_sizes, int n_in,
                              void* d_out, int out_size, void* d_ws,
                              size_t ws_size, hipStream_t stream) {
  const float* inp = (const float*)d_in[0];     // [2,2048,4096] fp32
  const float* W = (const float*)d_in[1];       // [4096,4096] fp32
  const float* conv_w = (const float*)d_in[2];  // [4,1,3,3] fp32
  const float* conv_b = (const float*)d_in[3];  // [4] fp32
  const float* sk_wt = (const float*)d_in[4];   // [4,1,1] fp32
  float* out = (float*)d_out;                   // [2,2048,4096] fp32

  __hip_bfloat16* Wt = (__hip_bfloat16*)d_ws;   // 32 MB
  __hip_bfloat16* Ab =
      (__hip_bfloat16*)((char*)d_ws + (size_t)(32u << 20));  // next 32 MB

  // 1) merged prep: cast activations + transform weight, one launch
  prep<<<CAST_BLOCKS + TRANS_BLOCKS, 256, 0, stream>>>(inp, Ab, W, conv_w,
                                                       conv_b, sk_wt, Wt);
  // 2) out[m][n] = sum_k Ab[m][k] * Wt[n][k]  (256x256 tiles, m201 8-phase)
  dim3 grid(FOUT / 256, M_DIM / 256);
  gemm_nt<<<grid, 512, 0, stream>>>(Ab, Wt, out, M_DIM, FOUT, FIN);
}

// Round 5
// 283.305 us; speedup vs baseline: 1.0368x; 1.0368x over previous
//
#include <hip/hip_runtime.h>
#include <hip/hip_bf16.h>

#define FIN 4096
#define FOUT 4096
#define HEADS 4
#define ROWS_PER_HEAD (FOUT / HEADS)  // 1024
#define M_DIM 4096                    // 2*2048 flattened batch*seq

typedef __attribute__((ext_vector_type(8))) short bf16x8;   // 8 bf16 = 4 VGPRs
typedef __attribute__((ext_vector_type(4))) float floatx4;  // MFMA accum

#define CAST_BLOCKS ((M_DIM * FIN) / (256 * 8))  // 8192
// R12: trans strip-mined 4 rows/block, half-row (2048 cols) per block:
// (4096/4 rows) * 2 col-halves = 2048 blocks.
#define TRANS_BLOCKS 2048

// ---------------------------------------------------------------------------
// Kernel 1 (merged prep). Cast half unchanged (R5-verified). Trans half
// R12-reworked: each block computes a 4-row x 2048-col strip of W_i, loading
// the 6 needed W rows ONCE into registers (1.5x read redundancy vs 3x for
// the old 1-row-per-block form), with an XCD-contiguous block swizzle so
// adjacent strips (sharing halo rows) land on the same XCD's L2.
// ---------------------------------------------------------------------------
__global__ __launch_bounds__(256) void prep(
    const float* __restrict__ x,    // activations [M_DIM][FIN]
    __hip_bfloat16* __restrict__ y, // bf16 activations out
    const float* __restrict__ W,
    const float* __restrict__ cw,   // [HEADS][3][3]
    const float* __restrict__ cb,   // [HEADS]
    const float* __restrict__ sk,   // [HEADS]
    __hip_bfloat16* __restrict__ Wt) {
  if (blockIdx.x < CAST_BLOCKS) {
    int idx = blockIdx.x * 256 + threadIdx.x;  // one per 8 elements
    const float4* xv = (const float4*)x;
    float4 a = xv[idx * 2];
    float4 b = xv[idx * 2 + 1];
    __hip_bfloat16 t[8];
    t[0] = __float2bfloat16(a.x); t[1] = __float2bfloat16(a.y);
    t[2] = __float2bfloat16(a.z); t[3] = __float2bfloat16(a.w);
    t[4] = __float2bfloat16(b.x); t[5] = __float2bfloat16(b.y);
    t[6] = __float2bfloat16(b.z); t[7] = __float2bfloat16(b.w);
    *(bf16x8*)(&y[(size_t)idx * 8]) = *(bf16x8*)t;
    return;
  }

  int tg = blockIdx.x - CAST_BLOCKS;  // 0..2047
  // XCD-contiguous swizzle: 256 consecutive work-items per XCD so strips
  // sharing halo rows hit the same XCD's L2 (dispatch is round-robin % 8).
  tg = (tg & 7) * (TRANS_BLOCKS / 8) + (tg >> 3);
  const int o0 = (tg >> 1) * 4;                      // base output row
  const int fs = (tg & 1) * 2048 + threadIdx.x * 8;  // col start
  const int h = o0 >> 10;                            // head (4 rows never
  const int r0 = o0 & (ROWS_PER_HEAD - 1);           //  straddle heads)

  float kk[3][3];
#pragma unroll
  for (int i = 0; i < 3; i++)
#pragma unroll
    for (int j = 0; j < 3; j++) kk[i][j] = cw[h * 9 + i * 3 + j];
  float sig = 1.0f / (1.0f + __expf(-sk[h]));
  float bias = cb[h];

  // Window of 6 W rows (in-head rows r0-1 .. r0+4), 10 cols (8 + halo).
  // Out-of-range rows zero-filled == conv zero-padding.
  float w[6][10];
#pragma unroll
  for (int i = 0; i < 6; i++) {
    int rr = r0 - 1 + i;
    if (rr < 0 || rr >= ROWS_PER_HEAD) {
#pragma unroll
      for (int c = 0; c < 10; c++) w[i][c] = 0.0f;
    } else {
      const float* rp = W + ((size_t)(h * ROWS_PER_HEAD + rr)) * FIN + fs;
      float4 v0 = *(const float4*)rp;
      float4 v1 = *(const float4*)(rp + 4);
      w[i][1] = v0.x; w[i][2] = v0.y; w[i][3] = v0.z; w[i][4] = v0.w;
      w[i][5] = v1.x; w[i][6] = v1.y; w[i][7] = v1.z; w[i][8] = v1.w;
      w[i][0] = (fs > 0) ? rp[-1] : 0.0f;
      w[i][9] = (fs + 8 < FIN) ? rp[8] : 0.0f;
    }
  }

#pragma unroll
  for (int j = 0; j < 4; j++) {  // output row o0+j; window center row j+1
    float acc[8];
#pragma unroll
    for (int c = 0; c < 8; c++) acc[c] = bias + sig * w[j + 1][c + 1];
#pragma unroll
    for (int dr = 0; dr < 3; dr++) {
#pragma unroll
      for (int c = 0; c < 8; c++)
        acc[c] += kk[dr][0] * w[j + dr][c] + kk[dr][1] * w[j + dr][c + 1] +
                  kk[dr][2] * w[j + dr][c + 2];
    }
    __hip_bfloat16 t[8];
#pragma unroll
    for (int c = 0; c < 8; c++) t[c] = __float2bfloat16(acc[c]);
    *(bf16x8*)(&Wt[(size_t)(o0 + j) * FIN + fs]) = *(bf16x8*)t;
  }
}

// ---------------------------------------------------------------------------
// Kernel 2: C[m][n] = sum_k A[m][k] * B[n][k]  (NT GEMM, bf16 in, FP32 out)
// R12 = R10 ring (verified 118 us, best) + one audited tweak: S_D (afr[0]
// k1-half; slot dead after C2) issues BEFORE C3 instead of after, deepening
// its read-ahead to ~2.5 clusters; C3's wait becomes lgkm(8) (outstanding
// S_B+S_C+S_D=12, wait-to-8 drains exactly S_B; DS ops retire in-order).
// All other structure byte-identical to R10. 8-phase family refuted on this
// problem (R8: 146 us, R11 faithful m201 port: 133 us vs ring 118 us).
// ---------------------------------------------------------------------------
__device__ static inline void gload_lds16(const void* g, void* l) {
  __builtin_amdgcn_global_load_lds(
      (const __attribute__((address_space(1))) void*)g,
      (__attribute__((address_space(3))) void*)l, 16, 0, 0);
}

#define BK 64
#define NT (FIN / BK)  // 64 K-tiles

__global__ __launch_bounds__(512, 2) void gemm_nt(
    const __hip_bfloat16* __restrict__ A,  // [M][K]
    const __hip_bfloat16* __restrict__ B,  // [N][K]  (= W_i, row-major)
    float* __restrict__ C,                 // [M][N] fp32
    int M, int N, int K) {
  // 8 distinct LDS objects (precise DMA alias info): 16 KB each, 128 KB.
  __shared__ __hip_bfloat16 As0h0[128 * BK];
  __shared__ __hip_bfloat16 As0h1[128 * BK];
  __shared__ __hip_bfloat16 As1h0[128 * BK];
  __shared__ __hip_bfloat16 As1h1[128 * BK];
  __shared__ __hip_bfloat16 Bs0h0[128 * BK];
  __shared__ __hip_bfloat16 Bs0h1[128 * BK];
  __shared__ __hip_bfloat16 Bs1h0[128 * BK];
  __shared__ __hip_bfloat16 Bs1h1[128 * BK];

  const int tid = threadIdx.x;
  const int lane = tid & 63;
  const int wave = tid >> 6;   // 0..7
  const int wr = wave >> 2;    // 0..1  (WARPS_M = 2)
  const int wn = wave & 3;     // 0..3  (WARPS_N = 4)
  const int fr = lane & 15;    // fragment row
  const int quad = lane >> 4;  // k-chunk selector
  const int sel = fr & 7;      // swizzle selector

  // XCD-chunked bijective swizzle (256 wgs % 8 == 0): 32 consecutive tiles
  // per XCD -> 2 A-panels (4 MB) L2-resident per XCD (mechanism confirmed
  // in R9: HBM BW 1490->990 GB/s at same FETCH).
  const int orig = blockIdx.y * gridDim.x + blockIdx.x;
  const int swz = (orig & 7) * 32 + (orig >> 3);
  const int tile_m = (swz >> 4) * 256;
  const int tile_n = (swz & 15) * 256;

  const __hip_bfloat16* At = A + (size_t)tile_m * K;  // SGPR base
  const __hip_bfloat16* Bt = B + (size_t)tile_n * K;

  // Staging invariants: chunk position p = c*512+tid; row=p>>3, slot=p&7
  // holds global chunk g = slot^(row&7)  (proven conflict-free swizzle).
  int soff[2], doff[2];
#pragma unroll
  for (int c = 0; c < 2; c++) {
    int p = c * 512 + tid;
    int row = p >> 3;
    int g = (p & 7) ^ (row & 7);
    soff[c] = row * K + g * 8;  // elems
    doff[c] = p * 8;            // elems into half-buffer
  }
  // Fragment read invariants (all local rows == fr mod 8 -> sel works).
  int aro[4], bro[2], co[2];
#pragma unroll
  for (int u = 0; u < 4; u++) aro[u] = (wr * 16 + u * 32 + fr) * 64;
#pragma unroll
  for (int j = 0; j < 2; j++) bro[j] = (wn * 16 + j * 64 + fr) * 64;
#pragma unroll
  for (int kk = 0; kk < 2; kk++) co[kk] = ((kk * 4 + quad) ^ sel) * 8;

  floatx4 acc[8][4];
#pragma unroll
  for (int i = 0; i < 8; i++)
#pragma unroll
    for (int j = 0; j < 4; j++) acc[i][j] = (floatx4){0.f, 0.f, 0.f, 0.f};

  // Fragment ring: afr[mslot][u] (A m-half, current k-half);
  // bfr[kslot][nh][j] (B both n-halves, per k-half slot).
  bf16x8 afr[2][4];
  bf16x8 bfr[2][2][2];

#define STAGE(GBASE, DST, TILE, HALF)                                    \
  do {                                                                   \
    const __hip_bfloat16* _s =                                           \
        GBASE + (size_t)(HALF) * 128 * K + (size_t)(TILE) * BK;          \
    _Pragma("unroll") for (int _c = 0; _c < 2; _c++) {                   \
      gload_lds16(_s + soff[_c], DST + doff[_c]);                        \
    }                                                                    \
  } while (0)

#define LOADA4(MS, SRC, KK)                                              \
  do {                                                                   \
    _Pragma("unroll") for (int _u = 0; _u < 4; _u++) {                   \
      afr[MS][_u] = *(const bf16x8*)&SRC[aro[_u] + co[KK]];              \
    }                                                                    \
  } while (0)

#define LOADB2(KS, NH, SRC, KK)                                          \
  do {                                                                   \
    _Pragma("unroll") for (int _j = 0; _j < 2; _j++) {                   \
      bfr[KS][NH][_j] = *(const bf16x8*)&SRC[bro[_j] + co[KK]];          \
    }                                                                    \
  } while (0)

#define MMA8(MS, KS, NH)                                                 \
  do {                                                                   \
    __builtin_amdgcn_s_setprio(1);                                       \
    _Pragma("unroll") for (int _u = 0; _u < 4; _u++) {                   \
      _Pragma("unroll") for (int _j = 0; _j < 2; _j++) {                 \
        acc[(MS) * 4 + _u][(NH) * 2 + _j] =                              \
            __builtin_amdgcn_mfma_f32_16x16x32_bf16(                     \
                afr[MS][_u], bfr[KS][NH][_j],                            \
                acc[(MS) * 4 + _u][(NH) * 2 + _j], 0, 0, 0);             \
      }                                                                  \
    }                                                                    \
    __builtin_amdgcn_s_setprio(0);                                       \
  } while (0)

#define BAR() __builtin_amdgcn_s_barrier()
#define WAITVM(N) asm volatile("s_waitcnt vmcnt(" #N ")" ::: "memory")
#define FENCE_LGKM(N)                                                    \
  do {                                                                   \
    __builtin_amdgcn_sched_barrier(0);                                   \
    asm volatile("s_waitcnt lgkmcnt(" #N ")" ::: "memory");              \
    __builtin_amdgcn_sched_barrier(0);                                   \
  } while (0)

  // One K-tile. Clusters C1..C7 here; C8 = MMA8(1,1,0) deferred past the
  // barrier (runs at the top of the NEXT tile body, hiding the read bubble).
  // Read segments: S_A(8: afr0 m0k0 + bfr0 k0) | S_B(4: afr1 m1k0) |
  // S_C(4: bfr1 k1) | S_D(4: afr0 m0k1) | S_E(4: afr1 m1k1).
  // Issue: [S_A] C1 [S_B] C2 [S_C S_D stagesA] C3 [] C4 [S_E] C5 [stagesB]
  // C6 [] C7. Waits: C1 lgkm(0); C3 needs S_B, outstanding 12 -> lgkm(8);
  // C5 needs S_C+S_D, outstanding 12 -> lgkm(4); C7 needs S_E -> lgkm(0).
  // Slot WAR (in-order issue guards): afr[0] m0k0 dies@C2 < S_D issue;
  // afr[1] m1k0 dies@C4 < S_E issue; bfr[1] prev-k1 dies@C8(top) < S_C;
  // bfr[0] prev-k0 dies@prev C4 < S_A. Stages -> buffers whose last reader
  // passed >=1 barrier ago; vmcnt(0)-equivalent coverage via WAITVM before
  // the tile barrier when staging.
#define TBODY(T, CA0, CA1, CB0, CB1, NA0, NA1, NB0, NB1, DO_C8, DO_STAGE) \
  do {                                                                    \
    LOADA4(0, CA0, 0);                                                    \
    LOADB2(0, 0, CB0, 0);                                                 \
    LOADB2(0, 1, CB1, 0);                                                 \
    if (DO_C8) MMA8(1, 1, 0); /* prev tile's C8 */                        \
    FENCE_LGKM(0);                                                        \
    MMA8(0, 0, 0); /* C1 */                                               \
    LOADA4(1, CA1, 0); /* S_B */                                          \
    MMA8(0, 0, 1); /* C2 */                                               \
    LOADB2(1, 0, CB0, 1); /* S_C */                                       \
    LOADB2(1, 1, CB1, 1);                                                 \
    LOADA4(0, CA0, 1); /* S_D (dead slot; deepened read-ahead) */         \
    if (DO_STAGE) {                                                       \
      STAGE(At, NA0, (T) + 1, 0);                                         \
      STAGE(At, NA1, (T) + 1, 1);                                         \
    }                                                                     \
    FENCE_LGKM(8);                                                        \
    MMA8(1, 0, 1); /* C3 */                                               \
    MMA8(1, 0, 0); /* C4 */                                               \
    LOADA4(1, CA1, 1); /* S_E */                                          \
    FENCE_LGKM(4);                                                        \
    MMA8(0, 1, 0); /* C5 */                                               \
    if (DO_STAGE) {                                                       \
      STAGE(Bt, NB0, (T) + 1, 0);                                         \
      STAGE(Bt, NB1, (T) + 1, 1);                                         \
    }                                                                     \
    MMA8(0, 1, 1); /* C6 */                                               \
    FENCE_LGKM(0);                                                        \
    MMA8(1, 1, 1); /* C7 */                                               \
    if (DO_STAGE) WAITVM(0);                                              \
    BAR();                                                                \
  } while (0)

  // ---- Prologue: stage tile0 fully into buf0.
  STAGE(At, As0h0, 0, 0);
  STAGE(At, As0h1, 0, 1);
  STAGE(Bt, Bs0h0, 0, 0);
  STAGE(Bt, Bs0h1, 0, 1);
  WAITVM(0);
  BAR();

  // ---- Tile 0 (buf0, no deferred C8 yet).
  TBODY(0, As0h0, As0h1, Bs0h0, Bs0h1, As1h0, As1h1, Bs1h0, Bs1h1, 0, 1);

  // ---- Tiles 1..62 as explicit (odd, even) pairs; compile-time buffers.
#pragma unroll 1
  for (int t = 1; t < NT - 1; t += 2) {
    TBODY(t, As1h0, As1h1, Bs1h0, Bs1h1, As0h0, As0h1, Bs0h0, Bs0h1, 1, 1);
    TBODY(t + 1, As0h0, As0h1, Bs0h0, Bs0h1, As1h0, As1h1, Bs1h0, Bs1h1, 1, 1);
  }

  // ---- Tile 63 (buf1): no staging, then the final deferred C8.
  TBODY(NT - 1, As1h0, As1h1, Bs1h0, Bs1h1, As0h0, As0h1, Bs0h0, Bs0h1, 1, 0);
  MMA8(1, 1, 0);  // tile 63's C8

#undef TBODY
#undef FENCE_LGKM
#undef STAGE
#undef LOADA4
#undef LOADB2
#undef MMA8
#undef BAR
#undef WAITVM

  // ---- Epilogue: C/D layout col = lane&15, row = quad*4 + reg.
#pragma unroll
  for (int i = 0; i < 8; i++) {
    int mb = tile_m + wr * 16 + i * 32 + quad * 4;
#pragma unroll
    for (int j = 0; j < 4; j++) {
      int n = tile_n + wn * 16 + j * 64 + fr;
#pragma unroll
      for (int r = 0; r < 4; r++) {
        C[(size_t)(mb + r) * N + n] = acc[i][j][r];
      }
    }
  }
}

// ---------------------------------------------------------------------------
extern "C" void kernel_launch(void* const* d_in, const int* in_sizes, int n_in,
                              void* d_out, int out_size, void* d_ws,
                              size_t ws_size, hipStream_t stream) {
  const float* inp = (const float*)d_in[0];     // [2,2048,4096] fp32
  const float* W = (const float*)d_in[1];       // [4096,4096] fp32
  const float* conv_w = (const float*)d_in[2];  // [4,1,3,3] fp32
  const float* conv_b = (const float*)d_in[3];  // [4] fp32
  const float* sk_wt = (const float*)d_in[4];   // [4,1,1] fp32
  float* out = (float*)d_out;                   // [2,2048,4096] fp32

  __hip_bfloat16* Wt = (__hip_bfloat16*)d_ws;   // 32 MB
  __hip_bfloat16* Ab =
      (__hip_bfloat16*)((char*)d_ws + (size_t)(32u << 20));  // next 32 MB

  // 1) merged prep: cast activations + transform weight, one launch
  prep<<<CAST_BLOCKS + TRANS_BLOCKS, 256, 0, stream>>>(inp, Ab, W, conv_w,
                                                       conv_b, sk_wt, Wt);
  // 2) out[m][n] = sum_k Ab[m][k] * Wt[n][k]  (256x256 tiles, ring schedule)
  dim3 grid(FOUT / 256, M_DIM / 256);
  gemm_nt<<<grid, 512, 0, stream>>>(Ab, Wt, out, M_DIM, FOUT, FIN);
}